// Round 17
// baseline (180.303 us; speedup 1.0000x reference)
//
#include <hip/hip_runtime.h>
#include <math.h>

#define D 64
#define EPS 1e-12f
#define LOG2E 1.4426950408889634f

typedef _Float16 half4_t __attribute__((ext_vector_type(4)));

// Full 16-lane sum via DPP (pure VALU, no LDS pipe / lgkmcnt).
__device__ __forceinline__ float dpp_sum16(float s) {
    int x;
    x = __builtin_amdgcn_update_dpp(__float_as_int(s), __float_as_int(s),
                                    0x124, 0xf, 0xf, false);  // row_ror:4
    s += __int_as_float(x);
    x = __builtin_amdgcn_update_dpp(__float_as_int(s), __float_as_int(s),
                                    0x128, 0xf, 0xf, false);  // row_ror:8
    s += __int_as_float(x);
    x = __builtin_amdgcn_update_dpp(__float_as_int(s), __float_as_int(s),
                                    0xB1, 0xf, 0xf, false);   // quad_perm [1,0,3,2]
    s += __int_as_float(x);
    x = __builtin_amdgcn_update_dpp(__float_as_int(s), __float_as_int(s),
                                    0x4E, 0xf, 0xf, false);   // quad_perm [2,3,0,1]
    s += __int_as_float(x);
    return s;
}

// prep1: inv_norm + fp16 copy of H. N*16 threads.
__global__ void prep1_kernel(const float4* __restrict__ H4,
                             float* __restrict__ inv_norm,
                             half4_t* __restrict__ Hh, int N, int do_conv) {
    int t = blockIdx.x * blockDim.x + threadIdx.x;
    if (t >= N * 16) return;
    int r = t >> 4, sub = t & 15;
    float4 v = H4[(size_t)r * 16 + sub];
    if (do_conv) {
        half4_t h;
        h[0] = (_Float16)v.x; h[1] = (_Float16)v.y;
        h[2] = (_Float16)v.z; h[3] = (_Float16)v.w;
        Hh[(size_t)r * 16 + sub] = h;
    }
    float ss = v.x * v.x + v.y * v.y + v.z * v.z + v.w * v.w;
    ss += __shfl_xor(ss, 1, 64);
    ss += __shfl_xor(ss, 2, 64);
    ss += __shfl_xor(ss, 4, 64);
    ss += __shfl_xor(ss, 8, 64);
    if (sub == 0) inv_norm[r] = 1.0f / fmaxf(sqrtf(ss), EPS);
}

// prep2: row_ptr + edge pair array {col byte-offset, inv_norm[col]*log2e}.
// E threads; depends on prep1's inv_norm (same stream serializes).
__global__ void prep2_kernel(const int* __restrict__ row,
                             const int* __restrict__ col,
                             const float* __restrict__ inv_norm,
                             int* __restrict__ row_ptr,
                             uint2* __restrict__ pairs,
                             int N, int E, int mode) {  // mode: 0 none,1 fp16,2 fp32
    int e = blockIdx.x * blockDim.x + threadIdx.x;
    if (e >= E) return;
    int cur  = row[e];
    int prev = (e == 0) ? -1 : row[e - 1];
    for (int r = prev + 1; r <= cur; ++r) row_ptr[r] = e;
    if (e == E - 1) {
        for (int r = cur + 1; r <= N; ++r) row_ptr[r] = E;
    }
    if (mode) {
        int c = col[e];
        uint2 pq;
        pq.x = (unsigned)c << (mode == 1 ? 7 : 8);
        pq.y = __float_as_uint(inv_norm[c] * LOG2E);
        pairs[e] = pq;
    }
}

// Fused score + softmax + aggregation. One wave per dst row, 4 groups of 16
// lanes, 8 slots per group => 32 edges per pass (deg<=32: single pass, no
// carried state). Load phase: 8 pair loads then 8 row loads, all issued
// back-to-back (2 wide dependency levels instead of a 2-deep trickle).
// Invalid slots: loads clamped to a valid edge, p nullified by cndmask.
template <bool FP16, bool PAIRS>
__global__ __launch_bounds__(256, 8) void agnn_kernel(
    const float* __restrict__ H,
    const half4_t* __restrict__ Hh,
    const float* __restrict__ inv_norm,
    const uint2* __restrict__ pairs,
    const int* __restrict__ col,
    const int* __restrict__ row_ptr,
    float* __restrict__ out, int N) {
    int wid  = (blockIdx.x * blockDim.x + threadIdx.x) >> 6;
    int lane = threadIdx.x & 63;
    if (wid >= N) return;
    int g   = lane >> 4;
    int sub = lane & 15;

    int start = row_ptr[wid];
    int end   = row_ptr[wid + 1];

    if (start >= end) {  // empty row: out must be zeros (d_out is poisoned)
        if (g == 0) {
            float4 z = {0.0f, 0.0f, 0.0f, 0.0f};
            ((float4*)out)[(size_t)wid * 16 + sub] = z;
        }
        return;
    }

    const char* Hb = FP16 ? (const char*)Hh : (const char*)H;
    unsigned subo  = (unsigned)sub << (FP16 ? 3 : 4);

    float4 hr = ((const float4*)H)[(size_t)wid * 16 + sub];  // exact fp32
    float inr = inv_norm[wid];
    hr.x *= inr; hr.y *= inr; hr.z *= inr; hr.w *= inr;

    float  l = 0.0f;
    float4 acc = {0.0f, 0.0f, 0.0f, 0.0f};
    int cl = end - 1;

    for (int base = start; base < end; base += 32) {
        // level 1: edge metadata (8 independent loads)
        unsigned off[8];
        float    inl[8];
        #pragma unroll
        for (int s = 0; s < 8; ++s) {
            int ee = min(base + g + 4 * s, cl);
            if constexpr (PAIRS) {
                uint2 pq = pairs[ee];
                off[s] = pq.x;
                inl[s] = __uint_as_float(pq.y);
            } else {
                int c  = col[ee];
                off[s] = (unsigned)c << (FP16 ? 7 : 8);
                inl[s] = inv_norm[c] * LOG2E;
            }
        }
        // level 2: gathered feature rows (8 independent loads)
        if constexpr (FP16) {
            half4_t hh[8];
            #pragma unroll
            for (int s = 0; s < 8; ++s)
                hh[s] = *(const half4_t*)(Hb + off[s] + subo);
            #pragma unroll
            for (int s = 0; s < 8; ++s) {
                float4 h;
                h.x = (float)hh[s][0]; h.y = (float)hh[s][1];
                h.z = (float)hh[s][2]; h.w = (float)hh[s][3];
                float sd = hr.x * h.x + hr.y * h.y + hr.z * h.z + hr.w * h.w;
                sd = dpp_sum16(sd);
                float p = exp2f(sd * inl[s]);
                p = (base + g + 4 * s < end) ? p : 0.0f;
                l += p;
                acc.x += p * h.x; acc.y += p * h.y;
                acc.z += p * h.z; acc.w += p * h.w;
            }
        } else {
            float4 h[8];
            #pragma unroll
            for (int s = 0; s < 8; ++s)
                h[s] = *(const float4*)(Hb + off[s] + subo);
            #pragma unroll
            for (int s = 0; s < 8; ++s) {
                float sd = hr.x * h[s].x + hr.y * h[s].y +
                           hr.z * h[s].z + hr.w * h[s].w;
                sd = dpp_sum16(sd);
                float p = exp2f(sd * inl[s]);
                p = (base + g + 4 * s < end) ? p : 0.0f;
                l += p;
                acc.x += p * h[s].x; acc.y += p * h[s].y;
                acc.z += p * h[s].z; acc.w += p * h[s].w;
            }
        }
    }

    // plain-sum merge across the 4 groups
    #pragma unroll
    for (int off2 = 16; off2 <= 32; off2 <<= 1) {
        l     += __shfl_xor(l, off2, 64);
        acc.x += __shfl_xor(acc.x, off2, 64);
        acc.y += __shfl_xor(acc.y, off2, 64);
        acc.z += __shfl_xor(acc.z, off2, 64);
        acc.w += __shfl_xor(acc.w, off2, 64);
    }

    if (g == 0) {
        float invl = 1.0f / l;  // start < end => l > 0
        float4 o;
        o.x = acc.x * invl; o.y = acc.y * invl;
        o.z = acc.z * invl; o.w = acc.w * invl;
        ((float4*)out)[(size_t)wid * 16 + sub] = o;
    }
}

extern "C" void kernel_launch(void* const* d_in, const int* in_sizes, int n_in,
                              void* d_out, int out_size, void* d_ws, size_t ws_size,
                              hipStream_t stream) {
    const float* H   = (const float*)d_in[0];
    const int*   row = (const int*)d_in[1];
    const int*   col = (const int*)d_in[2];
    float*       out = (float*)d_out;

    int N = in_sizes[0] / D;
    int E = in_sizes[1];

    // ws layout: [Hh: N*128][pairs: E*8][inv_norm: N*4][row_ptr: (N+1)*4]
    size_t hh_bytes   = (size_t)N * 16 * sizeof(half4_t);
    size_t pair_bytes = (size_t)E * sizeof(uint2);
    size_t tail_bytes = (size_t)N * 4 + (size_t)(N + 1) * 4;
    bool fit_full = ws_size >= hh_bytes + pair_bytes + tail_bytes;
    bool fit_fp16 = ws_size >= hh_bytes + tail_bytes;

    half4_t* Hh;
    uint2*   pairs;
    float*   inv_norm;
    int*     row_ptr;
    int      mode;
    if (fit_full) {
        Hh       = (half4_t*)d_ws;
        pairs    = (uint2*)((char*)d_ws + hh_bytes);
        inv_norm = (float*)((char*)d_ws + hh_bytes + pair_bytes);
        mode     = 1;
    } else if (fit_fp16) {
        Hh       = (half4_t*)d_ws;
        pairs    = (uint2*)d_ws;  // unused
        inv_norm = (float*)((char*)d_ws + hh_bytes);
        mode     = 0;
    } else {
        Hh       = (half4_t*)d_ws;  // unused
        pairs    = (uint2*)d_ws;    // unused
        inv_norm = (float*)d_ws;
        mode     = 0;
    }
    row_ptr = (int*)(inv_norm + N);

    prep1_kernel<<<(N * 16 + 255) / 256, 256, 0, stream>>>(
        (const float4*)H, inv_norm, Hh, N, fit_fp16 ? 1 : 0);
    prep2_kernel<<<(E + 255) / 256, 256, 0, stream>>>(
        row, col, inv_norm, row_ptr, pairs, N, E, mode);

    int blocks = (N + 3) / 4;
    if (fit_full) {
        agnn_kernel<true, true><<<blocks, 256, 0, stream>>>(
            H, Hh, inv_norm, pairs, col, row_ptr, out, N);
    } else if (fit_fp16) {
        agnn_kernel<true, false><<<blocks, 256, 0, stream>>>(
            H, Hh, inv_norm, pairs, col, row_ptr, out, N);
    } else {
        agnn_kernel<false, false><<<blocks, 256, 0, stream>>>(
            H, Hh, inv_norm, pairs, col, row_ptr, out, N);
    }
}

// Round 18
// 156.287 us; speedup vs baseline: 1.1537x; 1.1537x over previous
//
#include <hip/hip_runtime.h>
#include <math.h>

#define D 64
#define EPS 1e-12f
#define LOG2E 1.4426950408889634f

typedef _Float16 half4_t __attribute__((ext_vector_type(4)));

// Full 16-lane sum via DPP (pure VALU, no LDS pipe / lgkmcnt).
__device__ __forceinline__ float dpp_sum16(float s) {
    int x;
    x = __builtin_amdgcn_update_dpp(__float_as_int(s), __float_as_int(s),
                                    0x124, 0xf, 0xf, false);  // row_ror:4
    s += __int_as_float(x);
    x = __builtin_amdgcn_update_dpp(__float_as_int(s), __float_as_int(s),
                                    0x128, 0xf, 0xf, false);  // row_ror:8
    s += __int_as_float(x);
    x = __builtin_amdgcn_update_dpp(__float_as_int(s), __float_as_int(s),
                                    0xB1, 0xf, 0xf, false);   // quad_perm [1,0,3,2]
    s += __int_as_float(x);
    x = __builtin_amdgcn_update_dpp(__float_as_int(s), __float_as_int(s),
                                    0x4E, 0xf, 0xf, false);   // quad_perm [2,3,0,1]
    s += __int_as_float(x);
    return s;
}

// prep1: inv_norm + fp16 copy of H. N*16 threads.
__global__ void prep1_kernel(const float4* __restrict__ H4,
                             float* __restrict__ inv_norm,
                             half4_t* __restrict__ Hh, int N, int do_conv) {
    int t = blockIdx.x * blockDim.x + threadIdx.x;
    if (t >= N * 16) return;
    int r = t >> 4, sub = t & 15;
    float4 v = H4[(size_t)r * 16 + sub];
    if (do_conv) {
        half4_t h;
        h[0] = (_Float16)v.x; h[1] = (_Float16)v.y;
        h[2] = (_Float16)v.z; h[3] = (_Float16)v.w;
        Hh[(size_t)r * 16 + sub] = h;
    }
    float ss = v.x * v.x + v.y * v.y + v.z * v.z + v.w * v.w;
    ss += __shfl_xor(ss, 1, 64);
    ss += __shfl_xor(ss, 2, 64);
    ss += __shfl_xor(ss, 4, 64);
    ss += __shfl_xor(ss, 8, 64);
    if (sub == 0) inv_norm[r] = 1.0f / fmaxf(sqrtf(ss), EPS);
}

// prep2: row_ptr + edge pair array {col byte-offset, inv_norm[col]*log2e}.
// E threads; depends on prep1's inv_norm (same stream serializes).
__global__ void prep2_kernel(const int* __restrict__ row,
                             const int* __restrict__ col,
                             const float* __restrict__ inv_norm,
                             int* __restrict__ row_ptr,
                             uint2* __restrict__ pairs,
                             int N, int E, int mode) {  // mode: 0 none,1 fp16,2 fp32
    int e = blockIdx.x * blockDim.x + threadIdx.x;
    if (e >= E) return;
    int cur  = row[e];
    int prev = (e == 0) ? -1 : row[e - 1];
    for (int r = prev + 1; r <= cur; ++r) row_ptr[r] = e;
    if (e == E - 1) {
        for (int r = cur + 1; r <= N; ++r) row_ptr[r] = E;
    }
    if (mode) {
        int c = col[e];
        uint2 pq;
        pq.x = (unsigned)c << (mode == 1 ? 7 : 8);
        pq.y = __float_as_uint(inv_norm[c] * LOG2E);
        pairs[e] = pq;
    }
}

// Fused score + softmax + aggregation. One wave per dst row, 4 groups of 16
// lanes, 8 slots per group => 32 edges per pass. Load phase: 8 pair loads
// then 8 row loads issued back-to-back (ILP covers gather latency).
// launch_bounds(256,4): 128-VGPR cap — the 8-slot arrays (~60 live regs)
// MUST stay in registers; (256,8)'s 32-VGPR cap spilled them to scratch
// (round 17: WRITE_SIZE 25->197 MB, 90 us regression).
template <bool FP16, bool PAIRS>
__global__ __launch_bounds__(256, 4) void agnn_kernel(
    const float* __restrict__ H,
    const half4_t* __restrict__ Hh,
    const float* __restrict__ inv_norm,
    const uint2* __restrict__ pairs,
    const int* __restrict__ col,
    const int* __restrict__ row_ptr,
    float* __restrict__ out, int N) {
    int wid  = (blockIdx.x * blockDim.x + threadIdx.x) >> 6;
    int lane = threadIdx.x & 63;
    if (wid >= N) return;
    int g   = lane >> 4;
    int sub = lane & 15;

    int start = row_ptr[wid];
    int end   = row_ptr[wid + 1];

    if (start >= end) {  // empty row: out must be zeros (d_out is poisoned)
        if (g == 0) {
            float4 z = {0.0f, 0.0f, 0.0f, 0.0f};
            ((float4*)out)[(size_t)wid * 16 + sub] = z;
        }
        return;
    }

    const char* Hb = FP16 ? (const char*)Hh : (const char*)H;
    unsigned subo  = (unsigned)sub << (FP16 ? 3 : 4);

    float4 hr = ((const float4*)H)[(size_t)wid * 16 + sub];  // exact fp32
    float inr = inv_norm[wid];
    hr.x *= inr; hr.y *= inr; hr.z *= inr; hr.w *= inr;

    float  l = 0.0f;
    float4 acc = {0.0f, 0.0f, 0.0f, 0.0f};
    int cl = end - 1;

    for (int base = start; base < end; base += 32) {
        // level 1: edge metadata (8 independent loads)
        unsigned off[8];
        float    inl[8];
        #pragma unroll
        for (int s = 0; s < 8; ++s) {
            int ee = min(base + g + 4 * s, cl);
            if constexpr (PAIRS) {
                uint2 pq = pairs[ee];
                off[s] = pq.x;
                inl[s] = __uint_as_float(pq.y);
            } else {
                int c  = col[ee];
                off[s] = (unsigned)c << (FP16 ? 7 : 8);
                inl[s] = inv_norm[c] * LOG2E;
            }
        }
        // level 2: gathered feature rows (8 independent loads)
        if constexpr (FP16) {
            half4_t hh[8];
            #pragma unroll
            for (int s = 0; s < 8; ++s)
                hh[s] = *(const half4_t*)(Hb + off[s] + subo);
            #pragma unroll
            for (int s = 0; s < 8; ++s) {
                float4 h;
                h.x = (float)hh[s][0]; h.y = (float)hh[s][1];
                h.z = (float)hh[s][2]; h.w = (float)hh[s][3];
                float sd = hr.x * h.x + hr.y * h.y + hr.z * h.z + hr.w * h.w;
                sd = dpp_sum16(sd);
                float p = exp2f(sd * inl[s]);
                p = (base + g + 4 * s < end) ? p : 0.0f;
                l += p;
                acc.x += p * h.x; acc.y += p * h.y;
                acc.z += p * h.z; acc.w += p * h.w;
            }
        } else {
            float4 h[8];
            #pragma unroll
            for (int s = 0; s < 8; ++s)
                h[s] = *(const float4*)(Hb + off[s] + subo);
            #pragma unroll
            for (int s = 0; s < 8; ++s) {
                float sd = hr.x * h[s].x + hr.y * h[s].y +
                           hr.z * h[s].z + hr.w * h[s].w;
                sd = dpp_sum16(sd);
                float p = exp2f(sd * inl[s]);
                p = (base + g + 4 * s < end) ? p : 0.0f;
                l += p;
                acc.x += p * h[s].x; acc.y += p * h[s].y;
                acc.z += p * h[s].z; acc.w += p * h[s].w;
            }
        }
    }

    // plain-sum merge across the 4 groups
    #pragma unroll
    for (int off2 = 16; off2 <= 32; off2 <<= 1) {
        l     += __shfl_xor(l, off2, 64);
        acc.x += __shfl_xor(acc.x, off2, 64);
        acc.y += __shfl_xor(acc.y, off2, 64);
        acc.z += __shfl_xor(acc.z, off2, 64);
        acc.w += __shfl_xor(acc.w, off2, 64);
    }

    if (g == 0) {
        float invl = 1.0f / l;  // start < end => l > 0
        float4 o;
        o.x = acc.x * invl; o.y = acc.y * invl;
        o.z = acc.z * invl; o.w = acc.w * invl;
        ((float4*)out)[(size_t)wid * 16 + sub] = o;
    }
}

extern "C" void kernel_launch(void* const* d_in, const int* in_sizes, int n_in,
                              void* d_out, int out_size, void* d_ws, size_t ws_size,
                              hipStream_t stream) {
    const float* H   = (const float*)d_in[0];
    const int*   row = (const int*)d_in[1];
    const int*   col = (const int*)d_in[2];
    float*       out = (float*)d_out;

    int N = in_sizes[0] / D;
    int E = in_sizes[1];

    // ws layout: [Hh: N*128][pairs: E*8][inv_norm: N*4][row_ptr: (N+1)*4]
    size_t hh_bytes   = (size_t)N * 16 * sizeof(half4_t);
    size_t pair_bytes = (size_t)E * sizeof(uint2);
    size_t tail_bytes = (size_t)N * 4 + (size_t)(N + 1) * 4;
    bool fit_full = ws_size >= hh_bytes + pair_bytes + tail_bytes;
    bool fit_fp16 = ws_size >= hh_bytes + tail_bytes;

    half4_t* Hh;
    uint2*   pairs;
    float*   inv_norm;
    int*     row_ptr;
    int      mode;
    if (fit_full) {
        Hh       = (half4_t*)d_ws;
        pairs    = (uint2*)((char*)d_ws + hh_bytes);
        inv_norm = (float*)((char*)d_ws + hh_bytes + pair_bytes);
        mode     = 1;
    } else if (fit_fp16) {
        Hh       = (half4_t*)d_ws;
        pairs    = (uint2*)d_ws;  // unused
        inv_norm = (float*)((char*)d_ws + hh_bytes);
        mode     = 0;
    } else {
        Hh       = (half4_t*)d_ws;  // unused
        pairs    = (uint2*)d_ws;    // unused
        inv_norm = (float*)d_ws;
        mode     = 0;
    }
    row_ptr = (int*)(inv_norm + N);

    prep1_kernel<<<(N * 16 + 255) / 256, 256, 0, stream>>>(
        (const float4*)H, inv_norm, Hh, N, fit_fp16 ? 1 : 0);
    prep2_kernel<<<(E + 255) / 256, 256, 0, stream>>>(
        row, col, inv_norm, row_ptr, pairs, N, E, mode);

    int blocks = (N + 3) / 4;
    if (fit_full) {
        agnn_kernel<true, true><<<blocks, 256, 0, stream>>>(
            H, Hh, inv_norm, pairs, col, row_ptr, out, N);
    } else if (fit_fp16) {
        agnn_kernel<true, false><<<blocks, 256, 0, stream>>>(
            H, Hh, inv_norm, pairs, col, row_ptr, out, N);
    } else {
        agnn_kernel<false, false><<<blocks, 256, 0, stream>>>(
            H, Hh, inv_norm, pairs, col, row_ptr, out, N);
    }
}